// Round 1
// 1240.075 us; speedup vs baseline: 1.1141x; 1.1141x over previous
//
#include <hip/hip_runtime.h>
#include <math.h>

// Problem constants (LSTMBasedTextDecoder): B=32, T=128, E=256, H=512, ENC=512, V=10000
#define Bx   32
#define Tx   128
#define Ex   256
#define Hx   512
#define ENCx 512
#define Vx   10000
#define G4   2048   // 4*H

#define RBLK 64     // k_rec grid: 64 blocks, 8 h-units each (co-resident, 1 per CU)
#define UPB  8      // h-units per block
#define KREC 768    // fused recurrence K = H (512, h) + E (256, y)
#define KPAD 776    // LDS row pitch (bf16): 1552 B = 388 banks == 4 mod 32 -> 2-way (free)

typedef __bf16 bf16x8 __attribute__((ext_vector_type(8)));
typedef float  f32x4  __attribute__((ext_vector_type(4)));

#define MFMA16 __builtin_amdgcn_mfma_f32_16x16x32_bf16

__device__ __forceinline__ float sigm(float x) { return 1.0f / (1.0f + expf(-x)); }

// ---------------------------------------------------------------------------
// K0: o = tv@Wo^T+b (fp32 [b][j]); h0 -> hg0 bf16 [b][j]; c0 fp32 [j][b].
// ---------------------------------------------------------------------------
__global__ __launch_bounds__(256) void k_init(
    const float* __restrict__ tv,
    const float* __restrict__ Wo_w, const float* __restrict__ Wo_b,
    const float* __restrict__ Wh_w, const float* __restrict__ Wh_b,
    const float* __restrict__ Wc_w, const float* __restrict__ Wc_b,
    float* __restrict__ o, __bf16* __restrict__ hglob, float* __restrict__ c0) {
  int tid = blockIdx.x * blockDim.x + threadIdx.x;   // 3*B*H = 49152
  int which = tid / (Bx * Hx);
  int r = tid - which * (Bx * Hx);
  int b = r >> 9, j = r & (Hx - 1);
  const float* W; const float* bias;
  if (which == 0)      { W = Wo_w; bias = Wo_b; }
  else if (which == 1) { W = Wh_w; bias = Wh_b; }
  else                 { W = Wc_w; bias = Wc_b; }
  const float* x = tv + b * ENCx;
  const float* w = W + (size_t)j * ENCx;
  float acc = bias[j];
#pragma unroll 8
  for (int k = 0; k < ENCx; k++) acc += x[k] * w[k];
  if (which == 0)      o[b * Hx + j] = acc;
  else if (which == 1) hglob[b * Hx + j] = (__bf16)acc;
  else                 c0[j * Bx + b] = acc;
}

// ---------------------------------------------------------------------------
// K1: constC[b][g] = b_ih[g]+b_hh[g] + o[b]:W_ih[g,256:768] + tv[b]:W_ih[g,768:1280]
// (step-invariant preactivation part, fp32 exact). Also zeroes the RBLK
// barrier flags (ws is re-poisoned to 0xAA before every timed call).
// ---------------------------------------------------------------------------
__global__ __launch_bounds__(256) void k_const(
    const float* __restrict__ tv, const float* __restrict__ o,
    const float* __restrict__ W_ih, const float* __restrict__ b_ih,
    const float* __restrict__ b_hh, float* __restrict__ constC,
    int* __restrict__ flags) {
  int tid = blockIdx.x * blockDim.x + threadIdx.x;   // B*G4 = 65536
  if (tid < RBLK) flags[tid] = 0;
  int b = tid >> 11, g = tid & (G4 - 1);
  const float* w = W_ih + (size_t)g * (Ex + Hx + ENCx);
  float acc = b_ih[g] + b_hh[g];
  const float* ob = o + b * Hx;
#pragma unroll 8
  for (int k = 0; k < Hx; k++) acc += ob[k] * w[Ex + k];
  const float* xb = tv + b * ENCx;
#pragma unroll 8
  for (int k = 0; k < ENCx; k++) acc += xb[k] * w[Ex + Hx + k];
  constC[b * G4 + g] = acc;   // [b][g], g-fastest
}

// ---------------------------------------------------------------------------
// K_cvt: fp32 -> bf16, flat (n divisible by 4).
// ---------------------------------------------------------------------------
__global__ __launch_bounds__(256) void k_cvt(
    const float* __restrict__ src, __bf16* __restrict__ dst, int n) {
  int i = (blockIdx.x * blockDim.x + threadIdx.x) * 4;
  if (i < n) {
    float4 v = *(const float4*)(src + i);
    dst[i + 0] = (__bf16)v.x; dst[i + 1] = (__bf16)v.y;
    dst[i + 2] = (__bf16)v.z; dst[i + 3] = (__bf16)v.w;
  }
}

// K_cvt2d: W_ih[:, 0:256] (pitch 1280) -> dense bf16 [2048][256].
__global__ __launch_bounds__(256) void k_cvt2d(
    const float* __restrict__ src, __bf16* __restrict__ dst) {
  int idx = (blockIdx.x * 256 + threadIdx.x) * 4;   // 2048*256 elems
  int row = idx >> 8, col = idx & 255;
  float4 v = *(const float4*)(src + (size_t)row * 1280 + col);
  dst[idx + 0] = (__bf16)v.x; dst[idx + 1] = (__bf16)v.y;
  dst[idx + 2] = (__bf16)v.z; dst[idx + 3] = (__bf16)v.w;
}

// ---------------------------------------------------------------------------
// K2: the whole recurrence in ONE launch. 64 blocks x 256 threads, all
// co-resident. Block nb owns h-units u0..u0+7 => 32 gate rows n = ul*4+gate,
// staged once into LDS as [W_hh | W_ih[:,0:256]] bf16 (K=768). Per step:
// stage A=[h;y_t] (h double-buffered by step parity; y prefetched during the
// previous epilogue), 4 independent MFMA waves (m-tile x j-tile, full K=768,
// no cross-wave reduce), fp32 gate epilogue (c in regs), h (bf16) to global.
//
// Grid barrier: distributed flag array. Arrival = one RELEASE store (one
// wbl2, no RMW). Wait = 64 lanes poll flags[lane] with RELAXED agent loads
// (sc1, no per-poll cache maintenance; one coalesced 256 B load per round),
// then a single ACQUIRE fence (one buffer_inv) before re-reading h.
// constC slice and all tokens live in LDS -> zero per-step global reads
// besides the 32 KB h broadcast and the 8 KB y-embedding prefetch.
// ---------------------------------------------------------------------------
__global__ __launch_bounds__(256) void k_rec(
    const __bf16* __restrict__ Whb,   // [2048][512]
    const __bf16* __restrict__ Wihb,  // [2048][256]
    const __bf16* __restrict__ embb,  // [V][256]
    const int* __restrict__ texts, const int* __restrict__ sidx,
    const float* __restrict__ constC, // [32][2048]
    const float* __restrict__ c0,     // [512][32]
    __bf16* __restrict__ hg0,         // [32][512] state for even t
    __bf16* __restrict__ hg1,         // [32][512] state for odd t
    __bf16* __restrict__ hs2,         // [4096][512]  row m = b*128+t
    int* __restrict__ flags) {        // [RBLK]
  __shared__ __bf16 Ws[2 * 16][KPAD];
  __shared__ __bf16 Hs[32][KPAD];
  __shared__ float  Cs[32][33];
  __shared__ float  CsC[32][33];
  __shared__ __bf16 Ht[32][8];
  __shared__ int    tokL[Bx * Tx];

  const int q = threadIdx.x;
  const int nb = blockIdx.x;
  const int u0 = nb * UPB;
  const int lane = q & 63, wave = q >> 6;
  const int mt = wave & 1, jt = wave >> 1;          // m-tile, j-tile (independent)
  const int fm = lane & 15, fk = (lane >> 4) * 8;   // MFMA frag row / k-offset
  const int cr = (lane >> 4) * 4, cc = lane & 15;   // MFMA C layout
  const int s0tok = sidx[0];

  // ---- stage Ws once: LDS row n <- W row (n&3)*512 + u0 + (n>>2) ----
  {
    const int row = q >> 3;                          // 8 threads per row
    const int wr = (row & 3) * Hx + u0 + (row >> 2);
    const __bf16* wh = Whb + (size_t)wr * Hx;
    const __bf16* wy = Wihb + (size_t)wr * Ex;
#pragma unroll
    for (int r = 0; r < 12; r++) {
      const int col = ((q & 7) + 8 * r) * 8;         // 0..760
      bf16x8 v = (col < Hx) ? *(const bf16x8*)(wh + col)
                            : *(const bf16x8*)(wy + col - Hx);
      *(bf16x8*)&Ws[row][col] = v;
    }
  }
  // ---- all tokens -> LDS (kills per-step texts reads) ----
#pragma unroll
  for (int r = 0; r < 16; r++) tokL[q + 256 * r] = texts[q + 256 * r];
  // ---- this block's constC slice -> LDS (kills per-step scattered reads) ----
#pragma unroll
  for (int r = 0; r < 4; r++) {
    const int idx = q + 256 * r;                     // 0..1023
    const int b = idx >> 5, n = idx & 31;            // n = eu*4 + gate
    CsC[b][n] = constC[b * G4 + (n & 3) * Hx + u0 + (n >> 2)];
  }
  // ---- y(0) = emb[start] broadcast ----
#pragma unroll
  for (int r = 0; r < 4; r++) {
    const int vy = q + 256 * r;
    const int row = vy >> 5, col = (vy & 31) * 8;
    *(bf16x8*)&Hs[row][Hx + col] = *(const bf16x8*)(embb + (size_t)s0tok * Ex + col);
  }

  const int eb = q & 31, eu = q >> 5, eu4 = (q >> 5) * 4;   // epilogue (batch, u_local)
  float creg = c0[(u0 + eu) * Bx + eb];

  for (int t = 0; t < Tx; t++) {
    // ---- stage h-part of A from parity buffer (y already staged) ----
    const __bf16* hsrc = (t & 1) ? hg1 : hg0;
#pragma unroll
    for (int r = 0; r < 8; r++) {
      const int hv = q + 256 * r;
      const int row = hv >> 6, col = (hv & 63) * 8;
      *(bf16x8*)&Hs[row][col] = *(const bf16x8*)(hsrc + row * Hx + col);
    }
    __syncthreads();

    // ---- MFMA: wave (mt, jt) owns one 16x16 C tile over full K=768 ----
    f32x4 accA = {0.f, 0.f, 0.f, 0.f}, accB = {0.f, 0.f, 0.f, 0.f};
    const __bf16* ha = &Hs[mt * 16 + fm][0];
    const __bf16* wrow = &Ws[jt * 16 + fm][0];
#pragma unroll
    for (int ks = 0; ks < 24; ks += 2) {             // two chains for MFMA ILP
      accA = MFMA16(*(const bf16x8*)(ha + ks * 32 + fk),
                    *(const bf16x8*)(wrow + ks * 32 + fk), accA, 0, 0, 0);
      accB = MFMA16(*(const bf16x8*)(ha + ks * 32 + 32 + fk),
                    *(const bf16x8*)(wrow + ks * 32 + 32 + fk), accB, 0, 0, 0);
    }
    {
      const f32x4 acc = accA + accB;
#pragma unroll
      for (int r = 0; r < 4; r++) Cs[mt * 16 + cr + r][jt * 16 + cc] = acc[r];
    }
    __syncthreads();

    // ---- prefetch y(t+1) (independent of h) + fp32 gate epilogue ----
    bf16x8 yv[4];
    const int tn = t + 1;
    if (tn < Tx) {
#pragma unroll
      for (int r = 0; r < 4; r++) {
        const int vy = q + 256 * r;
        const int row = vy >> 5, col = (vy & 31) * 8;
        const int tok = tokL[row * Tx + tn - 1];
        yv[r] = *(const bf16x8*)(embb + (size_t)tok * Ex + col);
      }
    }
    {
      const float pi = Cs[eb][eu4 + 0] + CsC[eb][eu4 + 0];
      const float pf = Cs[eb][eu4 + 1] + CsC[eb][eu4 + 1];
      const float pg = Cs[eb][eu4 + 2] + CsC[eb][eu4 + 2];
      const float po = Cs[eb][eu4 + 3] + CsC[eb][eu4 + 3];
      const float cn = sigm(pf) * creg + sigm(pi) * tanhf(pg);
      creg = cn;
      Ht[eb][eu] = (__bf16)(sigm(po) * tanhf(cn));
    }
    if (tn < Tx) {
#pragma unroll
      for (int r = 0; r < 4; r++) {
        const int vy = q + 256 * r;
        const int row = vy >> 5, col = (vy & 31) * 8;
        *(bf16x8*)&Hs[row][Hx + col] = yv[r];
      }
    }
    __syncthreads();

    // ---- h slice to opposite parity buffer (wave 0); hs2 (wave 1, off the
    // release's vmcnt path — no intra-kernel reader) ----
    if (q < 32) {
      __bf16* hdst = (t & 1) ? hg0 : hg1;
      bf16x8 v = *(const bf16x8*)&Ht[q][0];
      *(bf16x8*)(hdst + q * Hx + u0) = v;
    } else if (q >= 64 && q < 96) {
      bf16x8 v = *(const bf16x8*)&Ht[q - 64][0];
      *(bf16x8*)(hs2 + ((size_t)(q - 64) * Tx + t) * Hx + u0) = v;
    }
    if (t < Tx - 1) {
      // arrival: release store (waits wave0 vmcnt -> h stores visible first)
      if (q == 0)
        __hip_atomic_store(&flags[nb], t + 1, __ATOMIC_RELEASE,
                           __HIP_MEMORY_SCOPE_AGENT);
      // wait: 64 lanes poll 64 flags (one coalesced load per round)
      if (q < RBLK) {
        int spins = 0;
        while (__hip_atomic_load(&flags[q], __ATOMIC_RELAXED,
                                 __HIP_MEMORY_SCOPE_AGENT) < t + 1) {
          __builtin_amdgcn_s_sleep(1);
          if ((++spins & 63) == 0)                    // progress insurance
            __builtin_amdgcn_fence(__ATOMIC_ACQUIRE, "agent");
        }
        __builtin_amdgcn_fence(__ATOMIC_ACQUIRE, "agent");  // one inv/step
      }
      __syncthreads();
    }
  }
}

// ---------------------------------------------------------------------------
// K3: logits = hs(bf16) @ Wv(bf16)^T + bias, MFMA 16x16x32.
// Grid: x = m-tile (fast) so the 32 blocks sharing a B n-tile run together;
// A (4 MB) stays L2/L3-hot -> near-minimal HBM fetch.
// ---------------------------------------------------------------------------
#define PM 128
#define PN 128
#define PK 32
#define PKP 40

__global__ __launch_bounds__(256) void k_proj_mfma(
    const __bf16* __restrict__ A,    // [4096][512]
    const __bf16* __restrict__ Bw,   // [10000][512]
    const float* __restrict__ bias, float* __restrict__ C) {
  __shared__ __bf16 As[PM][PKP];
  __shared__ __bf16 Bs[PN][PKP];
  const int m0 = blockIdx.x * PM;
  const int n0 = blockIdx.y * PN;
  const int t = threadIdx.x;
  const int wave = t >> 6, lane = t & 63;
  const int wm = (wave & 1) * 64, wn = (wave >> 1) * 64;
  const int fm = lane & 15, fk = (lane >> 4) * 8;
  const int sr = t >> 2, sk = (t & 3) * 8;

  const int n1 = min(n0 + sr, Vx - 1);
  const int n2 = min(n0 + sr + 64, Vx - 1);

  f32x4 acc[4][4];
#pragma unroll
  for (int i = 0; i < 4; i++)
#pragma unroll
    for (int j = 0; j < 4; j++) acc[i][j] = (f32x4){0.f, 0.f, 0.f, 0.f};

  for (int k0 = 0; k0 < Hx; k0 += PK) {
    __syncthreads();
    *(bf16x8*)&As[sr][sk]      = *(const bf16x8*)&A[(size_t)(m0 + sr) * Hx + k0 + sk];
    *(bf16x8*)&As[sr + 64][sk] = *(const bf16x8*)&A[(size_t)(m0 + sr + 64) * Hx + k0 + sk];
    *(bf16x8*)&Bs[sr][sk]      = *(const bf16x8*)&Bw[(size_t)n1 * Hx + k0 + sk];
    *(bf16x8*)&Bs[sr + 64][sk] = *(const bf16x8*)&Bw[(size_t)n2 * Hx + k0 + sk];
    __syncthreads();
    bf16x8 af[4], bfr[4];
#pragma unroll
    for (int i = 0; i < 4; i++) af[i]  = *(const bf16x8*)&As[wm + i * 16 + fm][fk];
#pragma unroll
    for (int j = 0; j < 4; j++) bfr[j] = *(const bf16x8*)&Bs[wn + j * 16 + fm][fk];
#pragma unroll
    for (int i = 0; i < 4; i++)
#pragma unroll
      for (int j = 0; j < 4; j++)
        acc[i][j] = MFMA16(af[i], bfr[j], acc[i][j], 0, 0, 0);
  }

  const int cr = (lane >> 4) * 4, cc = lane & 15;
#pragma unroll
  for (int i = 0; i < 4; i++) {
#pragma unroll
    for (int r = 0; r < 4; r++) {
      const int m = m0 + wm + i * 16 + cr + r;
      float* crow = C + (size_t)m * Vx;
#pragma unroll
      for (int j = 0; j < 4; j++) {
        const int n = n0 + wn + j * 16 + cc;
        if (n < Vx) crow[n] = acc[i][j][r] + bias[n];
      }
    }
  }
}

// ---------------------------------------------------------------------------
// Inputs (setup_inputs order):
//  0 text_vectors [32,512] f32   1 texts [32,128] i32   2 lengths (unused)
//  3 start_idx i32               4 emb_table [10000,256] f32
//  5 W_ih [2048,1280] 6 b_ih 7 W_hh [2048,512] 8 b_hh
//  9 Wo_w 10 Wo_b 11 Wh_w 12 Wh_b 13 Wc_w 14 Wc_b 15 Wv_w [10000,512] 16 Wv_b
// Output: logits [32,128,10000] f32. Workspace: ~23.2 MB.
// ---------------------------------------------------------------------------
extern "C" void kernel_launch(void* const* d_in, const int* in_sizes, int n_in,
                              void* d_out, int out_size, void* d_ws, size_t ws_size,
                              hipStream_t stream) {
  const float* tv     = (const float*)d_in[0];
  const int*   texts  = (const int*)d_in[1];
  const int*   sidx   = (const int*)d_in[3];
  const float* emb    = (const float*)d_in[4];
  const float* W_ih   = (const float*)d_in[5];
  const float* b_ih   = (const float*)d_in[6];
  const float* W_hh   = (const float*)d_in[7];
  const float* b_hh   = (const float*)d_in[8];
  const float* Wo_w   = (const float*)d_in[9];
  const float* Wo_b   = (const float*)d_in[10];
  const float* Wh_w   = (const float*)d_in[11];
  const float* Wh_b   = (const float*)d_in[12];
  const float* Wc_w   = (const float*)d_in[13];
  const float* Wc_b   = (const float*)d_in[14];
  const float* Wv_w   = (const float*)d_in[15];
  const float* Wv_b   = (const float*)d_in[16];
  float* out = (float*)d_out;

  float* ws     = (float*)d_ws;
  float* o      = ws;                 // 16384 f
  float* c0     = o + Bx * Hx;        // 16384 f
  float* constC = c0 + Hx * Bx;       // 65536 f
  int*   flags  = (int*)(constC + (size_t)Bx * G4);   // 512 f reserved
  __bf16* bfb   = (__bf16*)(ws + 98816);              // 16B-aligned
  __bf16* hg0   = bfb;                                // 32*512 (even-t state)
  __bf16* hs2   = hg0 + Bx * Hx;                      // 4096*512
  __bf16* Wvb   = hs2 + (size_t)Bx * Tx * Hx;         // 10000*512
  __bf16* Whb   = Wvb + (size_t)Vx * Hx;              // 2048*512
  __bf16* embb  = Whb + (size_t)G4 * Hx;              // 10000*256
  __bf16* Wihb  = embb + (size_t)Vx * Ex;             // 2048*256
  __bf16* hg1   = Wihb + (size_t)G4 * Ex;             // 32*512 (odd-t state)

  hipLaunchKernelGGL(k_cvt, dim3((Vx * Hx / 4 + 255) / 256), dim3(256), 0, stream,
                     Wv_w, Wvb, Vx * Hx);
  hipLaunchKernelGGL(k_cvt, dim3((G4 * Hx / 4 + 255) / 256), dim3(256), 0, stream,
                     W_hh, Whb, G4 * Hx);
  hipLaunchKernelGGL(k_cvt, dim3((Vx * Ex / 4 + 255) / 256), dim3(256), 0, stream,
                     emb, embb, Vx * Ex);
  hipLaunchKernelGGL(k_cvt2d, dim3(G4 * Ex / 4 / 256), dim3(256), 0, stream,
                     W_ih, Wihb);
  hipLaunchKernelGGL(k_init, dim3(192), dim3(256), 0, stream,
                     tv, Wo_w, Wo_b, Wh_w, Wh_b, Wc_w, Wc_b, o, hg0, c0);
  hipLaunchKernelGGL(k_const, dim3(256), dim3(256), 0, stream,
                     tv, o, W_ih, b_ih, b_hh, constC, flags);
  hipLaunchKernelGGL(k_rec, dim3(RBLK), dim3(256), 0, stream,
                     Whb, Wihb, embb, texts, sidx, constC, c0, hg0, hg1, hs2, flags);
  hipLaunchKernelGGL(k_proj_mfma, dim3((Bx * Tx) / PM, (Vx + PN - 1) / PN), dim3(256), 0, stream,
                     hs2, Wvb, Wv_b, out);
}

// Round 2
// 1001.148 us; speedup vs baseline: 1.3800x; 1.2387x over previous
//
#include <hip/hip_runtime.h>
#include <math.h>

// Problem constants (LSTMBasedTextDecoder): B=32, T=128, E=256, H=512, ENC=512, V=10000
#define Bx   32
#define Tx   128
#define Ex   256
#define Hx   512
#define ENCx 512
#define Vx   10000
#define G4   2048   // 4*H

#define RBLK 64     // k_rec grid: 64 blocks, 8 h-units each (co-resident, 1 per CU)
#define UPB  8      // h-units per block
#define KREC 768    // fused recurrence K = H (512, h) + E (256, y)
#define KPAD 776    // LDS row pitch (bf16): 1552 B = 388 banks == 4 mod 32 -> 2-way (free)

typedef __bf16 bf16x8 __attribute__((ext_vector_type(8)));
typedef float  f32x4  __attribute__((ext_vector_type(4)));

#define MFMA16 __builtin_amdgcn_mfma_f32_16x16x32_bf16

__device__ __forceinline__ float sigm(float x) { return 1.0f / (1.0f + expf(-x)); }

// Write-through store: bypass L1 (sc0) + write-through/bypass L2 (sc1).
// Lands at the coherence point (IF/L3) -> visible to all XCDs, no wbl2 needed.
__device__ __forceinline__ void store_u32_wt(uint32_t* p, uint32_t v) {
  asm volatile("global_store_dword %0, %1, off sc0 sc1" :: "v"(p), "v"(v) : "memory");
}
// Coherent load: bypass L1+L2, read from coherence point.
__device__ __forceinline__ uint32_t load_u32_coh(const uint32_t* p) {
  uint32_t v;
  asm volatile("global_load_dword %0, %1, off sc0 sc1\n\ts_waitcnt vmcnt(0)"
               : "=v"(v) : "v"(p) : "memory");
  return v;
}

// ---------------------------------------------------------------------------
// K0: o = tv@Wo^T+b (fp32 [b][j]); h0 -> hinit bf16 [b][j]; c0 fp32 [j][b].
// ---------------------------------------------------------------------------
__global__ __launch_bounds__(256) void k_init(
    const float* __restrict__ tv,
    const float* __restrict__ Wo_w, const float* __restrict__ Wo_b,
    const float* __restrict__ Wh_w, const float* __restrict__ Wh_b,
    const float* __restrict__ Wc_w, const float* __restrict__ Wc_b,
    float* __restrict__ o, __bf16* __restrict__ hinit, float* __restrict__ c0) {
  int tid = blockIdx.x * blockDim.x + threadIdx.x;   // 3*B*H = 49152
  int which = tid / (Bx * Hx);
  int r = tid - which * (Bx * Hx);
  int b = r >> 9, j = r & (Hx - 1);
  const float* W; const float* bias;
  if (which == 0)      { W = Wo_w; bias = Wo_b; }
  else if (which == 1) { W = Wh_w; bias = Wh_b; }
  else                 { W = Wc_w; bias = Wc_b; }
  const float* x = tv + b * ENCx;
  const float* w = W + (size_t)j * ENCx;
  float acc = bias[j];
#pragma unroll 8
  for (int k = 0; k < ENCx; k++) acc += x[k] * w[k];
  if (which == 0)      o[b * Hx + j] = acc;
  else if (which == 1) hinit[b * Hx + j] = (__bf16)acc;
  else                 c0[j * Bx + b] = acc;
}

// ---------------------------------------------------------------------------
// K1: constC[b][g] = b_ih[g]+b_hh[g] + o[b]:W_ih[g,256:768] + tv[b]:W_ih[g,768:1280]
// (step-invariant preactivation part, fp32 exact). Also zeroes the RBLK
// barrier flags (ws is re-poisoned to 0xAA before every timed call).
// ---------------------------------------------------------------------------
__global__ __launch_bounds__(256) void k_const(
    const float* __restrict__ tv, const float* __restrict__ o,
    const float* __restrict__ W_ih, const float* __restrict__ b_ih,
    const float* __restrict__ b_hh, float* __restrict__ constC,
    int* __restrict__ flags) {
  int tid = blockIdx.x * blockDim.x + threadIdx.x;   // B*G4 = 65536
  if (tid < RBLK) flags[tid] = 0;
  int b = tid >> 11, g = tid & (G4 - 1);
  const float* w = W_ih + (size_t)g * (Ex + Hx + ENCx);
  float acc = b_ih[g] + b_hh[g];
  const float* ob = o + b * Hx;
#pragma unroll 8
  for (int k = 0; k < Hx; k++) acc += ob[k] * w[Ex + k];
  const float* xb = tv + b * ENCx;
#pragma unroll 8
  for (int k = 0; k < ENCx; k++) acc += xb[k] * w[Ex + Hx + k];
  constC[b * G4 + g] = acc;   // [b][g], g-fastest
}

// ---------------------------------------------------------------------------
// K_cvt: fp32 -> bf16, flat (n divisible by 4).
// ---------------------------------------------------------------------------
__global__ __launch_bounds__(256) void k_cvt(
    const float* __restrict__ src, __bf16* __restrict__ dst, int n) {
  int i = (blockIdx.x * blockDim.x + threadIdx.x) * 4;
  if (i < n) {
    float4 v = *(const float4*)(src + i);
    dst[i + 0] = (__bf16)v.x; dst[i + 1] = (__bf16)v.y;
    dst[i + 2] = (__bf16)v.z; dst[i + 3] = (__bf16)v.w;
  }
}

// K_cvt2d: W_ih[:, 0:256] (pitch 1280) -> dense bf16 [2048][256].
__global__ __launch_bounds__(256) void k_cvt2d(
    const float* __restrict__ src, __bf16* __restrict__ dst) {
  int idx = (blockIdx.x * 256 + threadIdx.x) * 4;   // 2048*256 elems
  int row = idx >> 8, col = idx & 255;
  float4 v = *(const float4*)(src + (size_t)row * 1280 + col);
  dst[idx + 0] = (__bf16)v.x; dst[idx + 1] = (__bf16)v.y;
  dst[idx + 2] = (__bf16)v.z; dst[idx + 3] = (__bf16)v.w;
}

// ---------------------------------------------------------------------------
// K2: the whole recurrence in ONE launch. 64 blocks x 256 threads, all
// co-resident. Block nb owns h-units u0..u0+7 => 32 gate rows n = ul*4+gate,
// staged once into LDS as [W_hh | W_ih[:,0:256]] bf16 (K=768). Per step:
// stage A=[h;y_t] (y prefetched during the previous epilogue), 4 independent
// MFMA waves (m-tile x j-tile, full K=768), fp32 gate epilogue (c in regs).
//
// h exchange with ZERO cache-maintenance instructions (no wbl2/inv/fence):
//  - h(t) goes to a FRESH address each step: hs2 reorganized as [t][b][h]
//    (the store IS the hs2 output). Stores are write-through dwords
//    (sc0 sc1 -> coherence point directly).
//  - arrival: wave 0 stores its 512 B slice, s_waitcnt vmcnt(0) (data ack'd
//    at L3), then one relaxed write-through flag store. No buffer_wbl2.
//  - wait: wave 1 polls the 63 OTHER flags (own flag would cost an extra L3
//    round trip) with sc0 sc1 loads, concurrently with wave 0's stores; the
//    trailing __syncthreads joins. No buffer_inv: the h reload itself uses
//    sc0 sc1 dwordx4 loads (straight from L3, address never cached).
//  - side effect: Ws/embb/tokens/constC stay warm in L1/L2 for all 128 steps.
// ---------------------------------------------------------------------------
__global__ __launch_bounds__(256) void k_rec(
    const __bf16* __restrict__ Whb,   // [2048][512]
    const __bf16* __restrict__ Wihb,  // [2048][256]
    const __bf16* __restrict__ embb,  // [V][256]
    const int* __restrict__ texts, const int* __restrict__ sidx,
    const float* __restrict__ constC, // [32][2048]
    const float* __restrict__ c0,     // [512][32]
    const __bf16* __restrict__ hinit, // [32][512]
    __bf16* __restrict__ hs2,         // [128][32][512]  (t-major!)
    int* __restrict__ flags) {        // [RBLK]
  __shared__ __bf16 Ws[2 * 16][KPAD];
  __shared__ __bf16 Hs[32][KPAD];
  __shared__ float  Cs[32][33];
  __shared__ float  CsC[32][33];
  __shared__ __bf16 Ht[32][8];
  __shared__ int    tokL[Bx * Tx];

  const int q = threadIdx.x;
  const int nb = blockIdx.x;
  const int u0 = nb * UPB;
  const int lane = q & 63, wave = q >> 6;
  const int mt = wave & 1, jt = wave >> 1;          // m-tile, j-tile (independent)
  const int fm = lane & 15, fk = (lane >> 4) * 8;   // MFMA frag row / k-offset
  const int cr = (lane >> 4) * 4, cc = lane & 15;   // MFMA C layout
  const int s0tok = sidx[0];

  // ---- stage Ws once: LDS row n <- W row (n&3)*512 + u0 + (n>>2) ----
  {
    const int row = q >> 3;                          // 8 threads per row
    const int wr = (row & 3) * Hx + u0 + (row >> 2);
    const __bf16* wh = Whb + (size_t)wr * Hx;
    const __bf16* wy = Wihb + (size_t)wr * Ex;
#pragma unroll
    for (int r = 0; r < 12; r++) {
      const int col = ((q & 7) + 8 * r) * 8;         // 0..760
      bf16x8 v = (col < Hx) ? *(const bf16x8*)(wh + col)
                            : *(const bf16x8*)(wy + col - Hx);
      *(bf16x8*)&Ws[row][col] = v;
    }
  }
  // ---- all tokens -> LDS (kills per-step texts reads) ----
#pragma unroll
  for (int r = 0; r < 16; r++) tokL[q + 256 * r] = texts[q + 256 * r];
  // ---- this block's constC slice -> LDS (kills per-step scattered reads) ----
#pragma unroll
  for (int r = 0; r < 4; r++) {
    const int idx = q + 256 * r;                     // 0..1023
    const int b = idx >> 5, n = idx & 31;            // n = eu*4 + gate
    CsC[b][n] = constC[b * G4 + (n & 3) * Hx + u0 + (n >> 2)];
  }
  // ---- y(0) = emb[start] broadcast ----
#pragma unroll
  for (int r = 0; r < 4; r++) {
    const int vy = q + 256 * r;
    const int row = vy >> 5, col = (vy & 31) * 8;
    *(bf16x8*)&Hs[row][Hx + col] = *(const bf16x8*)(embb + (size_t)s0tok * Ex + col);
  }

  const int eb = q & 31, eu = q >> 5, eu4 = (q >> 5) * 4;   // epilogue (batch, u_local)
  float creg = c0[(u0 + eu) * Bx + eb];

  for (int t = 0; t < Tx; t++) {
    // ---- stage h-part of A: coherent loads straight from L3 ----
    {
      const __bf16* hsrc = (t == 0) ? hinit : hs2 + (size_t)(t - 1) * (Bx * Hx);
      bf16x8 hv[8];
#pragma unroll
      for (int r = 0; r < 8; r++) {
        const int hi = q + 256 * r;
        const __bf16* p = hsrc + (hi >> 6) * Hx + (hi & 63) * 8;
        asm volatile("global_load_dwordx4 %0, %1, off sc0 sc1"
                     : "=v"(hv[r]) : "v"(p) : "memory");
      }
      asm volatile("s_waitcnt vmcnt(0)" ::: "memory");
      __builtin_amdgcn_sched_barrier(0);
#pragma unroll
      for (int r = 0; r < 8; r++) {
        const int hi = q + 256 * r;
        *(bf16x8*)&Hs[hi >> 6][(hi & 63) * 8] = hv[r];
      }
    }
    __syncthreads();

    // ---- MFMA: wave (mt, jt) owns one 16x16 C tile over full K=768 ----
    f32x4 accA = {0.f, 0.f, 0.f, 0.f}, accB = {0.f, 0.f, 0.f, 0.f};
    const __bf16* ha = &Hs[mt * 16 + fm][0];
    const __bf16* wrow = &Ws[jt * 16 + fm][0];
#pragma unroll
    for (int ks = 0; ks < 24; ks += 2) {             // two chains for MFMA ILP
      accA = MFMA16(*(const bf16x8*)(ha + ks * 32 + fk),
                    *(const bf16x8*)(wrow + ks * 32 + fk), accA, 0, 0, 0);
      accB = MFMA16(*(const bf16x8*)(ha + ks * 32 + 32 + fk),
                    *(const bf16x8*)(wrow + ks * 32 + 32 + fk), accB, 0, 0, 0);
    }
    {
      const f32x4 acc = accA + accB;
#pragma unroll
      for (int r = 0; r < 4; r++) Cs[mt * 16 + cr + r][jt * 16 + cc] = acc[r];
    }
    __syncthreads();

    // ---- prefetch y(t+1) (independent of h) + fp32 gate epilogue ----
    bf16x8 yv[4];
    const int tn = t + 1;
    if (tn < Tx) {
#pragma unroll
      for (int r = 0; r < 4; r++) {
        const int vy = q + 256 * r;
        const int row = vy >> 5, col = (vy & 31) * 8;
        const int tok = tokL[row * Tx + tn - 1];
        yv[r] = *(const bf16x8*)(embb + (size_t)tok * Ex + col);
      }
    }
    {
      const float pi = Cs[eb][eu4 + 0] + CsC[eb][eu4 + 0];
      const float pf = Cs[eb][eu4 + 1] + CsC[eb][eu4 + 1];
      const float pg = Cs[eb][eu4 + 2] + CsC[eb][eu4 + 2];
      const float po = Cs[eb][eu4 + 3] + CsC[eb][eu4 + 3];
      const float cn = sigm(pf) * creg + sigm(pi) * tanhf(pg);
      creg = cn;
      Ht[eb][eu] = (__bf16)(sigm(po) * tanhf(cn));
    }
    if (tn < Tx) {
#pragma unroll
      for (int r = 0; r < 4; r++) {
        const int vy = q + 256 * r;
        const int row = vy >> 5, col = (vy & 31) * 8;
        *(bf16x8*)&Hs[row][Hx + col] = yv[r];
      }
    }
    __syncthreads();

    // ---- arrival (wave 0) || wait-for-others (wave 1) ----
    if (wave == 0) {
      uint32_t* dst = (uint32_t*)(hs2 + (size_t)t * (Bx * Hx));
#pragma unroll
      for (int r = 0; r < 2; r++) {
        const int idx = lane + 64 * r;               // 128 dwords = 32 b-rows x 16B
        const int b = idx >> 2, dw = idx & 3;
        const uint32_t val = *(const uint32_t*)&Ht[b][dw * 2];
        store_u32_wt(dst + (size_t)b * (Hx / 2) + (u0 >> 1) + dw, val);
      }
      asm volatile("s_waitcnt vmcnt(0)" ::: "memory");  // data ack'd at L3
      if (lane == 0 && t < Tx - 1)
        store_u32_wt((uint32_t*)&flags[nb], (uint32_t)(t + 1));
    } else if (wave == 1 && t < Tx - 1) {
      if (lane != nb) {                              // own flag: joined via barrier
        while ((int)load_u32_coh((const uint32_t*)&flags[lane]) < t + 1)
          __builtin_amdgcn_s_sleep(1);
      }
    }
    __syncthreads();
  }
}

// ---------------------------------------------------------------------------
// K3: logits = hs(bf16) @ Wv(bf16)^T + bias, MFMA 16x16x32.
// A is [t][b][h] (row = t*32+b); logical GEMM row m = b*128+t is remapped at
// the A-load only. A (4 MB, L3-resident from k_rec's write-through stores).
// ---------------------------------------------------------------------------
#define PM 128
#define PN 128
#define PK 32
#define PKP 40

__global__ __launch_bounds__(256) void k_proj_mfma(
    const __bf16* __restrict__ A,    // [4096][512], row = t*32+b
    const __bf16* __restrict__ Bw,   // [10000][512]
    const float* __restrict__ bias, float* __restrict__ C) {
  __shared__ __bf16 As[PM][PKP];
  __shared__ __bf16 Bs[PN][PKP];
  const int m0 = blockIdx.x * PM;
  const int n0 = blockIdx.y * PN;
  const int t = threadIdx.x;
  const int wave = t >> 6, lane = t & 63;
  const int wm = (wave & 1) * 64, wn = (wave >> 1) * 64;
  const int fm = lane & 15, fk = (lane >> 4) * 8;
  const int sr = t >> 2, sk = (t & 3) * 8;

  const int n1 = min(n0 + sr, Vx - 1);
  const int n2 = min(n0 + sr + 64, Vx - 1);
  const int g1 = m0 + sr, g2 = m0 + sr + 64;         // logical m = b*128+t
  const int r1 = ((g1 & 127) << 5) | (g1 >> 7);      // physical row t*32+b
  const int r2 = ((g2 & 127) << 5) | (g2 >> 7);

  f32x4 acc[4][4];
#pragma unroll
  for (int i = 0; i < 4; i++)
#pragma unroll
    for (int j = 0; j < 4; j++) acc[i][j] = (f32x4){0.f, 0.f, 0.f, 0.f};

  for (int k0 = 0; k0 < Hx; k0 += PK) {
    __syncthreads();
    *(bf16x8*)&As[sr][sk]      = *(const bf16x8*)&A[(size_t)r1 * Hx + k0 + sk];
    *(bf16x8*)&As[sr + 64][sk] = *(const bf16x8*)&A[(size_t)r2 * Hx + k0 + sk];
    *(bf16x8*)&Bs[sr][sk]      = *(const bf16x8*)&Bw[(size_t)n1 * Hx + k0 + sk];
    *(bf16x8*)&Bs[sr + 64][sk] = *(const bf16x8*)&Bw[(size_t)n2 * Hx + k0 + sk];
    __syncthreads();
    bf16x8 af[4], bfr[4];
#pragma unroll
    for (int i = 0; i < 4; i++) af[i]  = *(const bf16x8*)&As[wm + i * 16 + fm][fk];
#pragma unroll
    for (int j = 0; j < 4; j++) bfr[j] = *(const bf16x8*)&Bs[wn + j * 16 + fm][fk];
#pragma unroll
    for (int i = 0; i < 4; i++)
#pragma unroll
      for (int j = 0; j < 4; j++)
        acc[i][j] = MFMA16(af[i], bfr[j], acc[i][j], 0, 0, 0);
  }

  const int cr = (lane >> 4) * 4, cc = lane & 15;
#pragma unroll
  for (int i = 0; i < 4; i++) {
#pragma unroll
    for (int r = 0; r < 4; r++) {
      const int m = m0 + wm + i * 16 + cr + r;
      float* crow = C + (size_t)m * Vx;
#pragma unroll
      for (int j = 0; j < 4; j++) {
        const int n = n0 + wn + j * 16 + cc;
        if (n < Vx) crow[n] = acc[i][j][r] + bias[n];
      }
    }
  }
}

// ---------------------------------------------------------------------------
// Inputs (setup_inputs order):
//  0 text_vectors [32,512] f32   1 texts [32,128] i32   2 lengths (unused)
//  3 start_idx i32               4 emb_table [10000,256] f32
//  5 W_ih [2048,1280] 6 b_ih 7 W_hh [2048,512] 8 b_hh
//  9 Wo_w 10 Wo_b 11 Wh_w 12 Wh_b 13 Wc_w 14 Wc_b 15 Wv_w [10000,512] 16 Wv_b
// Output: logits [32,128,10000] f32. Workspace: ~23.2 MB.
// ---------------------------------------------------------------------------
extern "C" void kernel_launch(void* const* d_in, const int* in_sizes, int n_in,
                              void* d_out, int out_size, void* d_ws, size_t ws_size,
                              hipStream_t stream) {
  const float* tv     = (const float*)d_in[0];
  const int*   texts  = (const int*)d_in[1];
  const int*   sidx   = (const int*)d_in[3];
  const float* emb    = (const float*)d_in[4];
  const float* W_ih   = (const float*)d_in[5];
  const float* b_ih   = (const float*)d_in[6];
  const float* W_hh   = (const float*)d_in[7];
  const float* b_hh   = (const float*)d_in[8];
  const float* Wo_w   = (const float*)d_in[9];
  const float* Wo_b   = (const float*)d_in[10];
  const float* Wh_w   = (const float*)d_in[11];
  const float* Wh_b   = (const float*)d_in[12];
  const float* Wc_w   = (const float*)d_in[13];
  const float* Wc_b   = (const float*)d_in[14];
  const float* Wv_w   = (const float*)d_in[15];
  const float* Wv_b   = (const float*)d_in[16];
  float* out = (float*)d_out;

  float* ws     = (float*)d_ws;
  float* o      = ws;                 // 16384 f
  float* c0     = o + Bx * Hx;        // 16384 f
  float* constC = c0 + Hx * Bx;       // 65536 f
  int*   flags  = (int*)(constC + (size_t)Bx * G4);   // 512 f reserved
  __bf16* bfb   = (__bf16*)(ws + 98816);              // 16B-aligned
  __bf16* hinit = bfb;                                // 32*512 initial h
  __bf16* hs2   = hinit + Bx * Hx;                    // 128*32*512, [t][b][h]
  __bf16* Wvb   = hs2 + (size_t)Bx * Tx * Hx;         // 10000*512
  __bf16* Whb   = Wvb + (size_t)Vx * Hx;              // 2048*512
  __bf16* embb  = Whb + (size_t)G4 * Hx;              // 10000*256
  __bf16* Wihb  = embb + (size_t)Vx * Ex;             // 2048*256

  hipLaunchKernelGGL(k_cvt, dim3((Vx * Hx / 4 + 255) / 256), dim3(256), 0, stream,
                     Wv_w, Wvb, Vx * Hx);
  hipLaunchKernelGGL(k_cvt, dim3((G4 * Hx / 4 + 255) / 256), dim3(256), 0, stream,
                     W_hh, Whb, G4 * Hx);
  hipLaunchKernelGGL(k_cvt, dim3((Vx * Ex / 4 + 255) / 256), dim3(256), 0, stream,
                     emb, embb, Vx * Ex);
  hipLaunchKernelGGL(k_cvt2d, dim3(G4 * Ex / 4 / 256), dim3(256), 0, stream,
                     W_ih, Wihb);
  hipLaunchKernelGGL(k_init, dim3(192), dim3(256), 0, stream,
                     tv, Wo_w, Wo_b, Wh_w, Wh_b, Wc_w, Wc_b, o, hinit, c0);
  hipLaunchKernelGGL(k_const, dim3(256), dim3(256), 0, stream,
                     tv, o, W_ih, b_ih, b_hh, constC, flags);
  hipLaunchKernelGGL(k_rec, dim3(RBLK), dim3(256), 0, stream,
                     Whb, Wihb, embb, texts, sidx, constC, c0, hinit, hs2, flags);
  hipLaunchKernelGGL(k_proj_mfma, dim3((Bx * Tx) / PM, (Vx + PN - 1) / PN), dim3(256), 0, stream,
                     hs2, Wvb, Wv_b, out);
}

// Round 3
// 975.371 us; speedup vs baseline: 1.4165x; 1.0264x over previous
//
#include <hip/hip_runtime.h>
#include <math.h>

// Problem constants (LSTMBasedTextDecoder): B=32, T=128, E=256, H=512, ENC=512, V=10000
#define Bx   32
#define Tx   128
#define Ex   256
#define Hx   512
#define ENCx 512
#define Vx   10000
#define G4   2048   // 4*H

#define RBLK 64     // k_rec grid: 64 blocks, 8 h-units each (co-resident, 1 per CU)
#define UPB  8      // h-units per block
#define KREC 768    // fused recurrence K = H (512, h) + E (256, y)
#define KPAD 776    // LDS row pitch (bf16): 1552 B = 388 banks == 4 mod 32 -> 2-way (free)

typedef __bf16 bf16x8 __attribute__((ext_vector_type(8)));
typedef float  f32x4  __attribute__((ext_vector_type(4)));

#define MFMA16 __builtin_amdgcn_mfma_f32_16x16x32_bf16

__device__ __forceinline__ float sigm(float x) { return 1.0f / (1.0f + expf(-x)); }

// Write-through stores: bypass L1 (sc0) + L2 (sc1) -> land at the coherence
// point (fabric/MALL), visible to all XCDs without any wbl2/inv.
__device__ __forceinline__ void store_u32_wt(uint32_t* p, uint32_t v) {
  asm volatile("global_store_dword %0, %1, off sc0 sc1" :: "v"(p), "v"(v) : "memory");
}
__device__ __forceinline__ void store_b16_wt(__bf16* p, uint32_t v) {
  asm volatile("global_store_short %0, %1, off sc0 sc1" :: "v"(p), "v"(v) : "memory");
}

// ---------------------------------------------------------------------------
// K0: o = tv@Wo^T+b (fp32 [b][j]); h0 -> hinit bf16 [b][j]; c0 fp32 [j][b].
// ---------------------------------------------------------------------------
__global__ __launch_bounds__(256) void k_init(
    const float* __restrict__ tv,
    const float* __restrict__ Wo_w, const float* __restrict__ Wo_b,
    const float* __restrict__ Wh_w, const float* __restrict__ Wh_b,
    const float* __restrict__ Wc_w, const float* __restrict__ Wc_b,
    float* __restrict__ o, __bf16* __restrict__ hinit, float* __restrict__ c0) {
  int tid = blockIdx.x * blockDim.x + threadIdx.x;   // 3*B*H = 49152
  int which = tid / (Bx * Hx);
  int r = tid - which * (Bx * Hx);
  int b = r >> 9, j = r & (Hx - 1);
  const float* W; const float* bias;
  if (which == 0)      { W = Wo_w; bias = Wo_b; }
  else if (which == 1) { W = Wh_w; bias = Wh_b; }
  else                 { W = Wc_w; bias = Wc_b; }
  const float* x = tv + b * ENCx;
  const float* w = W + (size_t)j * ENCx;
  float acc = bias[j];
#pragma unroll 8
  for (int k = 0; k < ENCx; k++) acc += x[k] * w[k];
  if (which == 0)      o[b * Hx + j] = acc;
  else if (which == 1) hinit[b * Hx + j] = (__bf16)acc;
  else                 c0[j * Bx + b] = acc;
}

// ---------------------------------------------------------------------------
// K1: constC[b][g] = b_ih[g]+b_hh[g] + o[b]:W_ih[g,256:768] + tv[b]:W_ih[g,768:1280]
// (step-invariant preactivation part, fp32 exact). Also zeroes the RBLK
// barrier flags (ws is re-poisoned to 0xAA before every timed call).
// ---------------------------------------------------------------------------
__global__ __launch_bounds__(256) void k_const(
    const float* __restrict__ tv, const float* __restrict__ o,
    const float* __restrict__ W_ih, const float* __restrict__ b_ih,
    const float* __restrict__ b_hh, float* __restrict__ constC,
    int* __restrict__ flags) {
  int tid = blockIdx.x * blockDim.x + threadIdx.x;   // B*G4 = 65536
  if (tid < RBLK) flags[tid] = 0;
  int b = tid >> 11, g = tid & (G4 - 1);
  const float* w = W_ih + (size_t)g * (Ex + Hx + ENCx);
  float acc = b_ih[g] + b_hh[g];
  const float* ob = o + b * Hx;
#pragma unroll 8
  for (int k = 0; k < Hx; k++) acc += ob[k] * w[Ex + k];
  const float* xb = tv + b * ENCx;
#pragma unroll 8
  for (int k = 0; k < ENCx; k++) acc += xb[k] * w[Ex + Hx + k];
  constC[b * G4 + g] = acc;   // [b][g], g-fastest
}

// ---------------------------------------------------------------------------
// K_cvt: fp32 -> bf16, flat (n divisible by 4).
// ---------------------------------------------------------------------------
__global__ __launch_bounds__(256) void k_cvt(
    const float* __restrict__ src, __bf16* __restrict__ dst, int n) {
  int i = (blockIdx.x * blockDim.x + threadIdx.x) * 4;
  if (i < n) {
    float4 v = *(const float4*)(src + i);
    dst[i + 0] = (__bf16)v.x; dst[i + 1] = (__bf16)v.y;
    dst[i + 2] = (__bf16)v.z; dst[i + 3] = (__bf16)v.w;
  }
}

// K_cvt2d: W_ih[:, 0:256] (pitch 1280) -> dense bf16 [2048][256].
__global__ __launch_bounds__(256) void k_cvt2d(
    const float* __restrict__ src, __bf16* __restrict__ dst) {
  int idx = (blockIdx.x * 256 + threadIdx.x) * 4;   // 2048*256 elems
  int row = idx >> 8, col = idx & 255;
  float4 v = *(const float4*)(src + (size_t)row * 1280 + col);
  dst[idx + 0] = (__bf16)v.x; dst[idx + 1] = (__bf16)v.y;
  dst[idx + 2] = (__bf16)v.z; dst[idx + 3] = (__bf16)v.w;
}

// ---------------------------------------------------------------------------
// K2: the whole recurrence in ONE launch. 64 blocks x 256 threads, all
// co-resident. Block nb owns h-units u0..u0+7 => 32 gate rows, staged once
// into LDS as [W_hh | W_ih[:,0:256]] bf16 (K=768). Per step: MFMA (4 waves,
// one 16x16 C tile each, K=768), fp32 gate epilogue (c and constC in regs),
// each epilogue thread write-through-stores its own bf16 h directly to
// hs2[t] (eu-fast -> 16B coalesced chunks).
//
// Exchange (zero cache-maintenance, validated r2 protocol, now pipelined):
//  - drain: per-thread vmcnt(0) + __syncthreads (all 16KB of h(t) ack'd at
//    the coherence point), then q0 write-through-stores flags[nb]=t+1.
//  - progressive loader: wave w owns source slices w*16..w*16+15 (h columns
//    [w*128, w*128+128)). Loop: issue flag dword loads (lanes 0..15; own
//    flag treated ready) -> vmcnt(0) (drains PREVIOUS round's slice loads
//    too -> flag RT and slice RT overlap) -> ds_write landed slices ->
//    ballot -> issue loads for newly-ready slice PAIRS (64 lanes x dwordx4,
//    2 adjacent slices = 32 rows x 32B). Slices from fast blocks are
//    loaded while stragglers are still being polled.
//  - correctness: a slice load is only issued after its flag (stored after
//    the producer's vmcnt-drain) is observed -> data is at fabric; hs2[t]
//    addresses are fresh each step -> no stale-cache reuse (r2-validated).
// ---------------------------------------------------------------------------
__global__ __launch_bounds__(256) void k_rec(
    const __bf16* __restrict__ Whb,   // [2048][512]
    const __bf16* __restrict__ Wihb,  // [2048][256]
    const __bf16* __restrict__ embb,  // [V][256]
    const int* __restrict__ texts, const int* __restrict__ sidx,
    const float* __restrict__ constC, // [32][2048]
    const float* __restrict__ c0,     // [512][32]
    const __bf16* __restrict__ hinit, // [32][512]
    __bf16* __restrict__ hs2,         // [128][32][512]  (t-major!)
    int* __restrict__ flags) {        // [RBLK]
  __shared__ __bf16 Ws[2 * 16][KPAD];
  __shared__ __bf16 Hs[32][KPAD];
  __shared__ float  Cs[32][33];
  __shared__ int    tokL[Bx * Tx];

  const int q = threadIdx.x;
  const int nb = blockIdx.x;
  const int u0 = nb * UPB;
  const int lane = q & 63, wave = q >> 6;
  const int mt = wave & 1, jt = wave >> 1;          // m-tile, j-tile (independent)
  const int fm = lane & 15, fk = (lane >> 4) * 8;   // MFMA frag row / k-offset
  const int cr = (lane >> 4) * 4, cc = lane & 15;   // MFMA C layout
  const int s0tok = sidx[0];

  // ---- stage Ws once: LDS row n <- W row (n&3)*512 + u0 + (n>>2) ----
  {
    const int row = q >> 3;                          // 8 threads per row
    const int wr = (row & 3) * Hx + u0 + (row >> 2);
    const __bf16* wh = Whb + (size_t)wr * Hx;
    const __bf16* wy = Wihb + (size_t)wr * Ex;
#pragma unroll
    for (int r = 0; r < 12; r++) {
      const int col = ((q & 7) + 8 * r) * 8;         // 0..760
      bf16x8 v = (col < Hx) ? *(const bf16x8*)(wh + col)
                            : *(const bf16x8*)(wy + col - Hx);
      *(bf16x8*)&Ws[row][col] = v;
    }
  }
  // ---- all tokens -> LDS ----
#pragma unroll
  for (int r = 0; r < 16; r++) tokL[q + 256 * r] = texts[q + 256 * r];
  // ---- h(-1) = hinit -> Hs (normal cached loads, cross-kernel visible) ----
#pragma unroll
  for (int r = 0; r < 8; r++) {
    const int hv = q + 256 * r;
    const int row = hv >> 6, col = (hv & 63) * 8;
    *(bf16x8*)&Hs[row][col] = *(const bf16x8*)(hinit + row * Hx + col);
  }
  // ---- y(0) = emb[start] broadcast ----
#pragma unroll
  for (int r = 0; r < 4; r++) {
    const int vy = q + 256 * r;
    const int row = vy >> 5, col = (vy & 31) * 8;
    *(bf16x8*)&Hs[row][Hx + col] = *(const bf16x8*)(embb + (size_t)s0tok * Ex + col);
  }

  // ---- epilogue thread mapping: eu-fast for coalesced 2B stores ----
  const int eb = q >> 3, eu = q & 7, eu4 = (q & 7) * 4;
  float creg = c0[(u0 + eu) * Bx + eb];
  const float cc0v = constC[eb * G4 + 0 * Hx + u0 + eu];
  const float cc1v = constC[eb * G4 + 1 * Hx + u0 + eu];
  const float cc2v = constC[eb * G4 + 2 * Hx + u0 + eu];
  const float cc3v = constC[eb * G4 + 3 * Hx + u0 + eu];

  __syncthreads();

  for (int t = 0; t < Tx; t++) {
    // ---- MFMA: wave (mt, jt) owns one 16x16 C tile over full K=768 ----
    f32x4 accA = {0.f, 0.f, 0.f, 0.f}, accB = {0.f, 0.f, 0.f, 0.f};
    const __bf16* ha = &Hs[mt * 16 + fm][0];
    const __bf16* wrow = &Ws[jt * 16 + fm][0];
#pragma unroll
    for (int ks = 0; ks < 24; ks += 2) {             // two chains for MFMA ILP
      accA = MFMA16(*(const bf16x8*)(ha + ks * 32 + fk),
                    *(const bf16x8*)(wrow + ks * 32 + fk), accA, 0, 0, 0);
      accB = MFMA16(*(const bf16x8*)(ha + ks * 32 + 32 + fk),
                    *(const bf16x8*)(wrow + ks * 32 + 32 + fk), accB, 0, 0, 0);
    }
    {
      const f32x4 acc = accA + accB;
#pragma unroll
      for (int r = 0; r < 4; r++) Cs[mt * 16 + cr + r][jt * 16 + cc] = acc[r];
    }
    __syncthreads();

    // ---- y(t+1) prefetch + fp32 gate epilogue + direct WT h store ----
    bf16x8 yv[4];
    const int tn = t + 1;
    if (tn < Tx) {
#pragma unroll
      for (int r = 0; r < 4; r++) {
        const int vy = q + 256 * r;
        const int row = vy >> 5, col = (vy & 31) * 8;
        const int tok = tokL[row * Tx + tn - 1];
        yv[r] = *(const bf16x8*)(embb + (size_t)tok * Ex + col);
      }
    }
    {
      const float pi = Cs[eb][eu4 + 0] + cc0v;
      const float pf = Cs[eb][eu4 + 1] + cc1v;
      const float pg = Cs[eb][eu4 + 2] + cc2v;
      const float po = Cs[eb][eu4 + 3] + cc3v;
      const float cn = sigm(pf) * creg + sigm(pi) * tanhf(pg);
      creg = cn;
      const __bf16 hb = (__bf16)(sigm(po) * tanhf(cn));
      const uint32_t hu = (uint32_t)__builtin_bit_cast(unsigned short, hb);
      store_b16_wt(hs2 + (size_t)t * (Bx * Hx) + eb * Hx + u0 + eu, hu);
    }
    if (tn < Tx) {
#pragma unroll
      for (int r = 0; r < 4; r++) {
        const int vy = q + 256 * r;
        const int row = vy >> 5, col = (vy & 31) * 8;
        *(bf16x8*)&Hs[row][Hx + col] = yv[r];
      }
    }
    asm volatile("s_waitcnt vmcnt(0)" ::: "memory");  // per-thread h-store drain
    __syncthreads();                                  // all 16KB of h(t) ack'd

    // ---- flag out + pipelined progressive h(t) gather ----
    if (t < Tx - 1) {
      if (q == 0) store_u32_wt((uint32_t*)&flags[nb], t + 1);
      const __bf16* src = hs2 + (size_t)t * (Bx * Hx);
      const int sbase = wave * 16;
      const int myfl = (nb >= sbase && nb < sbase + 16) ? (nb - sbase) : -1;
      const int prow = lane >> 1, phalf = lane & 1;
      bf16x8 pv0, pv1, pv2, pv3, pv4, pv5, pv6, pv7;
      uint32_t done = 0, prevm = 0;
      for (;;) {
        uint32_t fv = 0;
        const bool last = ((done | prevm) == 0xFFu);
        if (!last && lane < 16) {
          if (lane == myfl) {
            fv = 0x7FFFFFFFu;
          } else {
            const uint32_t* fp = (const uint32_t*)&flags[sbase + lane];
            asm volatile("global_load_dword %0, %1, off sc0 sc1"
                         : "=v"(fv) : "v"(fp));
          }
        }
        asm volatile("s_waitcnt vmcnt(0)" ::: "memory");  // prev slices + flags
        __builtin_amdgcn_sched_barrier(0);
#define WR_P(P) if (prevm & (1u << P)) \
  *(bf16x8*)&Hs[prow][(sbase + 2 * P) * 8 + phalf * 8] = pv##P;
        WR_P(0) WR_P(1) WR_P(2) WR_P(3) WR_P(4) WR_P(5) WR_P(6) WR_P(7)
#undef WR_P
        done |= prevm;
        if (done == 0xFFu) break;
        const bool rdy = (lane < 16) && ((int)fv >= t + 1);
        const unsigned long long bl = __ballot(rdy);
        const uint32_t r16 = (uint32_t)bl & 0xFFFFu;
        const uint32_t x = r16 & (r16 >> 1);
        const uint32_t pairm = (x & 1u) | ((x >> 1) & 2u) | ((x >> 2) & 4u)
                             | ((x >> 3) & 8u) | ((x >> 4) & 16u)
                             | ((x >> 5) & 32u) | ((x >> 6) & 64u)
                             | ((x >> 7) & 128u);
        const uint32_t newm = pairm & ~done;
        prevm = newm;
#define LD_P(P) if (newm & (1u << P)) { \
  const __bf16* p_ = src + prow * Hx + (sbase + 2 * P) * 8 + phalf * 8; \
  asm volatile("global_load_dwordx4 %0, %1, off sc0 sc1" : "=v"(pv##P) : "v"(p_)); }
        LD_P(0) LD_P(1) LD_P(2) LD_P(3) LD_P(4) LD_P(5) LD_P(6) LD_P(7)
#undef LD_P
      }
    }
    __syncthreads();
  }
}

// ---------------------------------------------------------------------------
// K3: logits = hs(bf16) @ Wv(bf16)^T + bias, MFMA 16x16x32.
// A is [t][b][h] (row = t*32+b); logical GEMM row m = b*128+t is remapped at
// the A-load only. A (4 MB, coherence-point-resident from k_rec's stores).
// ---------------------------------------------------------------------------
#define PM 128
#define PN 128
#define PK 32
#define PKP 40

__global__ __launch_bounds__(256) void k_proj_mfma(
    const __bf16* __restrict__ A,    // [4096][512], row = t*32+b
    const __bf16* __restrict__ Bw,   // [10000][512]
    const float* __restrict__ bias, float* __restrict__ C) {
  __shared__ __bf16 As[PM][PKP];
  __shared__ __bf16 Bs[PN][PKP];
  const int m0 = blockIdx.x * PM;
  const int n0 = blockIdx.y * PN;
  const int t = threadIdx.x;
  const int wave = t >> 6, lane = t & 63;
  const int wm = (wave & 1) * 64, wn = (wave >> 1) * 64;
  const int fm = lane & 15, fk = (lane >> 4) * 8;
  const int sr = t >> 2, sk = (t & 3) * 8;

  const int n1 = min(n0 + sr, Vx - 1);
  const int n2 = min(n0 + sr + 64, Vx - 1);
  const int g1 = m0 + sr, g2 = m0 + sr + 64;         // logical m = b*128+t
  const int r1 = ((g1 & 127) << 5) | (g1 >> 7);      // physical row t*32+b
  const int r2 = ((g2 & 127) << 5) | (g2 >> 7);

  f32x4 acc[4][4];
#pragma unroll
  for (int i = 0; i < 4; i++)
#pragma unroll
    for (int j = 0; j < 4; j++) acc[i][j] = (f32x4){0.f, 0.f, 0.f, 0.f};

  for (int k0 = 0; k0 < Hx; k0 += PK) {
    __syncthreads();
    *(bf16x8*)&As[sr][sk]      = *(const bf16x8*)&A[(size_t)r1 * Hx + k0 + sk];
    *(bf16x8*)&As[sr + 64][sk] = *(const bf16x8*)&A[(size_t)r2 * Hx + k0 + sk];
    *(bf16x8*)&Bs[sr][sk]      = *(const bf16x8*)&Bw[(size_t)n1 * Hx + k0 + sk];
    *(bf16x8*)&Bs[sr + 64][sk] = *(const bf16x8*)&Bw[(size_t)n2 * Hx + k0 + sk];
    __syncthreads();
    bf16x8 af[4], bfr[4];
#pragma unroll
    for (int i = 0; i < 4; i++) af[i]  = *(const bf16x8*)&As[wm + i * 16 + fm][fk];
#pragma unroll
    for (int j = 0; j < 4; j++) bfr[j] = *(const bf16x8*)&Bs[wn + j * 16 + fm][fk];
#pragma unroll
    for (int i = 0; i < 4; i++)
#pragma unroll
      for (int j = 0; j < 4; j++)
        acc[i][j] = MFMA16(af[i], bfr[j], acc[i][j], 0, 0, 0);
  }

  const int cr = (lane >> 4) * 4, cc = lane & 15;
#pragma unroll
  for (int i = 0; i < 4; i++) {
#pragma unroll
    for (int r = 0; r < 4; r++) {
      const int m = m0 + wm + i * 16 + cr + r;
      float* crow = C + (size_t)m * Vx;
#pragma unroll
      for (int j = 0; j < 4; j++) {
        const int n = n0 + wn + j * 16 + cc;
        if (n < Vx) crow[n] = acc[i][j][r] + bias[n];
      }
    }
  }
}

// ---------------------------------------------------------------------------
// Inputs (setup_inputs order):
//  0 text_vectors [32,512] f32   1 texts [32,128] i32   2 lengths (unused)
//  3 start_idx i32               4 emb_table [10000,256] f32
//  5 W_ih [2048,1280] 6 b_ih 7 W_hh [2048,512] 8 b_hh
//  9 Wo_w 10 Wo_b 11 Wh_w 12 Wh_b 13 Wc_w 14 Wc_b 15 Wv_w [10000,512] 16 Wv_b
// Output: logits [32,128,10000] f32. Workspace: ~23.2 MB.
// ---------------------------------------------------------------------------
extern "C" void kernel_launch(void* const* d_in, const int* in_sizes, int n_in,
                              void* d_out, int out_size, void* d_ws, size_t ws_size,
                              hipStream_t stream) {
  const float* tv     = (const float*)d_in[0];
  const int*   texts  = (const int*)d_in[1];
  const int*   sidx   = (const int*)d_in[3];
  const float* emb    = (const float*)d_in[4];
  const float* W_ih   = (const float*)d_in[5];
  const float* b_ih   = (const float*)d_in[6];
  const float* W_hh   = (const float*)d_in[7];
  const float* b_hh   = (const float*)d_in[8];
  const float* Wo_w   = (const float*)d_in[9];
  const float* Wo_b   = (const float*)d_in[10];
  const float* Wh_w   = (const float*)d_in[11];
  const float* Wh_b   = (const float*)d_in[12];
  const float* Wc_w   = (const float*)d_in[13];
  const float* Wc_b   = (const float*)d_in[14];
  const float* Wv_w   = (const float*)d_in[15];
  const float* Wv_b   = (const float*)d_in[16];
  float* out = (float*)d_out;

  float* ws     = (float*)d_ws;
  float* o      = ws;                 // 16384 f
  float* c0     = o + Bx * Hx;        // 16384 f
  float* constC = c0 + Hx * Bx;       // 65536 f
  int*   flags  = (int*)(constC + (size_t)Bx * G4);   // 512 f reserved
  __bf16* bfb   = (__bf16*)(ws + 98816);              // 16B-aligned
  __bf16* hinit = bfb;                                // 32*512 initial h
  __bf16* hs2   = hinit + Bx * Hx;                    // 128*32*512, [t][b][h]
  __bf16* Wvb   = hs2 + (size_t)Bx * Tx * Hx;         // 10000*512
  __bf16* Whb   = Wvb + (size_t)Vx * Hx;              // 2048*512
  __bf16* embb  = Whb + (size_t)G4 * Hx;              // 10000*256
  __bf16* Wihb  = embb + (size_t)Vx * Ex;             // 2048*256

  hipLaunchKernelGGL(k_cvt, dim3((Vx * Hx / 4 + 255) / 256), dim3(256), 0, stream,
                     Wv_w, Wvb, Vx * Hx);
  hipLaunchKernelGGL(k_cvt, dim3((G4 * Hx / 4 + 255) / 256), dim3(256), 0, stream,
                     W_hh, Whb, G4 * Hx);
  hipLaunchKernelGGL(k_cvt, dim3((Vx * Ex / 4 + 255) / 256), dim3(256), 0, stream,
                     emb, embb, Vx * Ex);
  hipLaunchKernelGGL(k_cvt2d, dim3(G4 * Ex / 4 / 256), dim3(256), 0, stream,
                     W_ih, Wihb);
  hipLaunchKernelGGL(k_init, dim3(192), dim3(256), 0, stream,
                     tv, Wo_w, Wo_b, Wh_w, Wh_b, Wc_w, Wc_b, o, hinit, c0);
  hipLaunchKernelGGL(k_const, dim3(256), dim3(256), 0, stream,
                     tv, o, W_ih, b_ih, b_hh, constC, flags);
  hipLaunchKernelGGL(k_rec, dim3(RBLK), dim3(256), 0, stream,
                     Whb, Wihb, embb, texts, sidx, constC, c0, hinit, hs2, flags);
  hipLaunchKernelGGL(k_proj_mfma, dim3((Bx * Tx) / PM, (Vx + PN - 1) / PN), dim3(256), 0, stream,
                     hs2, Wvb, Wv_b, out);
}

// Round 4
// 865.734 us; speedup vs baseline: 1.5959x; 1.1266x over previous
//
#include <hip/hip_runtime.h>
#include <math.h>

// Problem constants (LSTMBasedTextDecoder): B=32, T=128, E=256, H=512, ENC=512, V=10000
#define Bx   32
#define Tx   128
#define Ex   256
#define Hx   512
#define ENCx 512
#define Vx   10000
#define G4   2048   // 4*H

#define RBLK 64     // k_rec grid: 64 blocks, 8 h-units each (co-resident, 1 per CU)
#define UPB  8      // h-units per block
#define KREC 768    // fused recurrence K = H (512, h) + E (256, y)
#define KPAD 776    // LDS row pitch (bf16): 1552 B = 388 banks == 4 mod 32 -> 2-way (free)

typedef __bf16 bf16x8 __attribute__((ext_vector_type(8)));
typedef float  f32x4  __attribute__((ext_vector_type(4)));
typedef uint32_t u32x4 __attribute__((ext_vector_type(4)));

#define MFMA16 __builtin_amdgcn_mfma_f32_16x16x32_bf16

__device__ __forceinline__ float sigm(float x) { return 1.0f / (1.0f + expf(-x)); }

// Write-through store: bypass L1 (sc0) + L2 (sc1) -> lands at the coherence
// point (fabric/L3), visible to all XCDs without any wbl2/inv.
__device__ __forceinline__ void store_u32_wt(uint32_t* p, uint32_t v) {
  asm volatile("global_store_dword %0, %1, off sc0 sc1" :: "v"(p), "v"(v) : "memory");
}

// ---------------------------------------------------------------------------
// K0: o = tv@Wo^T+b (fp32 [b][j]); h0 -> hinit bf16 [b][j]; c0 fp32 [j][b].
// ---------------------------------------------------------------------------
__global__ __launch_bounds__(256) void k_init(
    const float* __restrict__ tv,
    const float* __restrict__ Wo_w, const float* __restrict__ Wo_b,
    const float* __restrict__ Wh_w, const float* __restrict__ Wh_b,
    const float* __restrict__ Wc_w, const float* __restrict__ Wc_b,
    float* __restrict__ o, __bf16* __restrict__ hinit, float* __restrict__ c0) {
  int tid = blockIdx.x * blockDim.x + threadIdx.x;   // 3*B*H = 49152
  int which = tid / (Bx * Hx);
  int r = tid - which * (Bx * Hx);
  int b = r >> 9, j = r & (Hx - 1);
  const float* W; const float* bias;
  if (which == 0)      { W = Wo_w; bias = Wo_b; }
  else if (which == 1) { W = Wh_w; bias = Wh_b; }
  else                 { W = Wc_w; bias = Wc_b; }
  const float* x = tv + b * ENCx;
  const float* w = W + (size_t)j * ENCx;
  float acc = bias[j];
#pragma unroll 8
  for (int k = 0; k < ENCx; k++) acc += x[k] * w[k];
  if (which == 0)      o[b * Hx + j] = acc;
  else if (which == 1) hinit[b * Hx + j] = (__bf16)acc;
  else                 c0[j * Bx + b] = acc;
}

// ---------------------------------------------------------------------------
// K1: constC[b][g] = b_ih[g]+b_hh[g] + o[b]:W_ih[g,256:768] + tv[b]:W_ih[g,768:1280]
// (step-invariant preactivation part, fp32 exact). Also zeroes the tagged
// h-exchange buffer (tag 0 != any live tag 1..128; belt-and-suspenders on
// top of the 0xAA workspace re-poison).
// ---------------------------------------------------------------------------
__global__ __launch_bounds__(256) void k_const(
    const float* __restrict__ tv, const float* __restrict__ o,
    const float* __restrict__ W_ih, const float* __restrict__ b_ih,
    const float* __restrict__ b_hh, float* __restrict__ constC,
    uint32_t* __restrict__ tgd) {
  int tid = blockIdx.x * blockDim.x + threadIdx.x;   // B*G4 = 65536
  if (tid < 2 * Bx * Hx) tgd[tid] = 0;               // 32768 dwords
  int b = tid >> 11, g = tid & (G4 - 1);
  const float* w = W_ih + (size_t)g * (Ex + Hx + ENCx);
  float acc = b_ih[g] + b_hh[g];
  const float* ob = o + b * Hx;
#pragma unroll 8
  for (int k = 0; k < Hx; k++) acc += ob[k] * w[Ex + k];
  const float* xb = tv + b * ENCx;
#pragma unroll 8
  for (int k = 0; k < ENCx; k++) acc += xb[k] * w[Ex + Hx + k];
  constC[b * G4 + g] = acc;   // [b][g], g-fastest
}

// ---------------------------------------------------------------------------
// K_cvt: fp32 -> bf16, flat (n divisible by 4).
// ---------------------------------------------------------------------------
__global__ __launch_bounds__(256) void k_cvt(
    const float* __restrict__ src, __bf16* __restrict__ dst, int n) {
  int i = (blockIdx.x * blockDim.x + threadIdx.x) * 4;
  if (i < n) {
    float4 v = *(const float4*)(src + i);
    dst[i + 0] = (__bf16)v.x; dst[i + 1] = (__bf16)v.y;
    dst[i + 2] = (__bf16)v.z; dst[i + 3] = (__bf16)v.w;
  }
}

// K_cvt2d: W_ih[:, 0:256] (pitch 1280) -> dense bf16 [2048][256].
__global__ __launch_bounds__(256) void k_cvt2d(
    const float* __restrict__ src, __bf16* __restrict__ dst) {
  int idx = (blockIdx.x * 256 + threadIdx.x) * 4;   // 2048*256 elems
  int row = idx >> 8, col = idx & 255;
  float4 v = *(const float4*)(src + (size_t)row * 1280 + col);
  dst[idx + 0] = (__bf16)v.x; dst[idx + 1] = (__bf16)v.y;
  dst[idx + 2] = (__bf16)v.z; dst[idx + 3] = (__bf16)v.w;
}

// ---------------------------------------------------------------------------
// K2: the whole recurrence in ONE launch. 64 blocks x 256 threads, all
// co-resident. Block nb owns h-units u0..u0+7 => 32 gate rows, staged once
// into LDS as [W_hh | W_ih[:,0:256]] bf16 (K=768). Per step: MFMA (4 waves,
// one 16x16 C tile each, K=768), fp32 gate epilogue (c and constC in regs).
//
// h exchange: SELF-VALIDATING TAGGED DATA — no flags, no acks, no fences.
//  - producer: each epilogue thread write-through-stores its h as one dword
//    ((t+1)<<16 | bf16bits) into tgd[t&1] (dword stores are atomic -> tag
//    and payload can't tear). Fire-and-forget: no vmcnt, no flag store.
//    Plus one plain cached store of h into hs2[t] for k_proj (cross-kernel
//    visibility via dispatch-boundary writeback).
//  - consumer: wave w gathers h columns [w*128,(w+1)*128) x 32 rows as 16
//    dwordx4 sc0 sc1 loads/lane; vmcnt(0); accept a chunk iff all 4 tags
//    == t+1; reissue only misses. Detection and data transfer are the SAME
//    load -> the flag-detect round trip is gone.
//  - correctness: parity double-buffer. A block can never be 2 steps ahead
//    (its gather of step t needs every block's step-t epilogue), so WAR on
//    tgd[p] is impossible. Stale tags (t-1 from two steps ago), zeroed tags,
//    and 0xAAAA poison all != t+1.
// ---------------------------------------------------------------------------
__global__ __launch_bounds__(256) void k_rec(
    const __bf16* __restrict__ Whb,   // [2048][512]
    const __bf16* __restrict__ Wihb,  // [2048][256]
    const __bf16* __restrict__ embb,  // [V][256]
    const int* __restrict__ texts, const int* __restrict__ sidx,
    const float* __restrict__ constC, // [32][2048]
    const float* __restrict__ c0,     // [512][32]
    const __bf16* __restrict__ hinit, // [32][512]
    __bf16* __restrict__ hs2,         // [128][32][512]  (t-major)
    uint32_t* __restrict__ tgd) {     // [2][32][512] tagged dwords
  __shared__ __bf16 Ws[2 * 16][KPAD];
  __shared__ __bf16 Hs[32][KPAD];
  __shared__ float  Cs[32][33];
  __shared__ int    tokL[Bx * Tx];

  const int q = threadIdx.x;
  const int nb = blockIdx.x;
  const int u0 = nb * UPB;
  const int lane = q & 63, wave = q >> 6;
  const int mt = wave & 1, jt = wave >> 1;          // m-tile, j-tile (independent)
  const int fm = lane & 15, fk = (lane >> 4) * 8;   // MFMA frag row / k-offset
  const int cr = (lane >> 4) * 4, cc = lane & 15;   // MFMA C layout
  const int s0tok = sidx[0];

  // ---- stage Ws once: LDS row n <- W row (n&3)*512 + u0 + (n>>2) ----
  {
    const int row = q >> 3;                          // 8 threads per row
    const int wr = (row & 3) * Hx + u0 + (row >> 2);
    const __bf16* wh = Whb + (size_t)wr * Hx;
    const __bf16* wy = Wihb + (size_t)wr * Ex;
#pragma unroll
    for (int r = 0; r < 12; r++) {
      const int col = ((q & 7) + 8 * r) * 8;         // 0..760
      bf16x8 v = (col < Hx) ? *(const bf16x8*)(wh + col)
                            : *(const bf16x8*)(wy + col - Hx);
      *(bf16x8*)&Ws[row][col] = v;
    }
  }
  // ---- all tokens -> LDS ----
#pragma unroll
  for (int r = 0; r < 16; r++) tokL[q + 256 * r] = texts[q + 256 * r];
  // ---- h(-1) = hinit -> Hs (normal cached loads, cross-kernel visible) ----
#pragma unroll
  for (int r = 0; r < 8; r++) {
    const int hv = q + 256 * r;
    const int row = hv >> 6, col = (hv & 63) * 8;
    *(bf16x8*)&Hs[row][col] = *(const bf16x8*)(hinit + row * Hx + col);
  }
  // ---- y(0) = emb[start] broadcast ----
#pragma unroll
  for (int r = 0; r < 4; r++) {
    const int vy = q + 256 * r;
    const int row = vy >> 5, col = (vy & 31) * 8;
    *(bf16x8*)&Hs[row][Hx + col] = *(const bf16x8*)(embb + (size_t)s0tok * Ex + col);
  }

  // ---- epilogue thread mapping: eu-fast for coalesced stores ----
  const int eb = q >> 3, eu = q & 7, eu4 = (q & 7) * 4;
  float creg = c0[(u0 + eu) * Bx + eb];
  const float cc0v = constC[eb * G4 + 0 * Hx + u0 + eu];
  const float cc1v = constC[eb * G4 + 1 * Hx + u0 + eu];
  const float cc2v = constC[eb * G4 + 2 * Hx + u0 + eu];
  const float cc3v = constC[eb * G4 + 3 * Hx + u0 + eu];

  __syncthreads();

  for (int t = 0; t < Tx; t++) {
    // ---- MFMA: wave (mt, jt) owns one 16x16 C tile over full K=768 ----
    f32x4 accA = {0.f, 0.f, 0.f, 0.f}, accB = {0.f, 0.f, 0.f, 0.f};
    const __bf16* ha = &Hs[mt * 16 + fm][0];
    const __bf16* wrow = &Ws[jt * 16 + fm][0];
#pragma unroll
    for (int ks = 0; ks < 24; ks += 2) {             // two chains for MFMA ILP
      accA = MFMA16(*(const bf16x8*)(ha + ks * 32 + fk),
                    *(const bf16x8*)(wrow + ks * 32 + fk), accA, 0, 0, 0);
      accB = MFMA16(*(const bf16x8*)(ha + ks * 32 + 32 + fk),
                    *(const bf16x8*)(wrow + ks * 32 + 32 + fk), accB, 0, 0, 0);
    }
    {
      const f32x4 acc = accA + accB;
#pragma unroll
      for (int r = 0; r < 4; r++) Cs[mt * 16 + cr + r][jt * 16 + cc] = acc[r];
    }
    __syncthreads();                                  // S1: Cs ready, Hs-reads done

    // ---- fp32 gate epilogue + tagged WT store (fire-and-forget) ----
    {
      const float pi = Cs[eb][eu4 + 0] + cc0v;
      const float pf = Cs[eb][eu4 + 1] + cc1v;
      const float pg = Cs[eb][eu4 + 2] + cc2v;
      const float po = Cs[eb][eu4 + 3] + cc3v;
      const float cn = sigm(pf) * creg + sigm(pi) * tanhf(pg);
      creg = cn;
      const __bf16 hb = (__bf16)(sigm(po) * tanhf(cn));
      const uint32_t hu = (uint32_t)__builtin_bit_cast(unsigned short, hb);
      store_u32_wt(tgd + (size_t)(t & 1) * (Bx * Hx) + eb * Hx + u0 + eu,
                   ((uint32_t)(t + 1) << 16) | hu);
      hs2[(size_t)t * (Bx * Hx) + eb * Hx + u0 + eu] = hb;  // plain cached
    }
    // ---- y(t+1) -> Hs (cached embb loads; disjoint from gather range) ----
    if (t + 1 < Tx) {
#pragma unroll
      for (int r = 0; r < 4; r++) {
        const int vy = q + 256 * r;
        const int row = vy >> 5, col = (vy & 31) * 8;
        const int tok = tokL[row * Tx + t];
        *(bf16x8*)&Hs[row][Hx + col] = *(const bf16x8*)(embb + (size_t)tok * Ex + col);
      }
      // ---- gather h(t): poll the tagged data itself ----
      const uint32_t* src = tgd + (size_t)(t & 1) * (Bx * Hx);
      const uint32_t want = (uint32_t)(t + 1);
      u32x4 vv[16];
      uint32_t miss = 0xFFFFu;
      for (;;) {
#pragma unroll
        for (int i = 0; i < 16; i++) if (miss & (1u << i)) {
          const int c = i * 64 + lane;               // chunk: row=c>>5, 4 dwords
          const uint32_t* p_ = src + (c >> 5) * Hx + wave * 128 + (c & 31) * 4;
          asm volatile("global_load_dwordx4 %0, %1, off sc0 sc1"
                       : "=v"(vv[i]) : "v"(p_));
        }
        asm volatile("s_waitcnt vmcnt(0)" ::: "memory");
        __builtin_amdgcn_sched_barrier(0);
        uint32_t nmiss = 0;
#pragma unroll
        for (int i = 0; i < 16; i++) if (miss & (1u << i)) {
          const bool ok = (vv[i].x >> 16) == want && (vv[i].y >> 16) == want &&
                          (vv[i].z >> 16) == want && (vv[i].w >> 16) == want;
          if (!ok) nmiss |= (1u << i);
        }
        miss = nmiss;
        if (__ballot(miss != 0) == 0) break;
      }
#pragma unroll
      for (int i = 0; i < 16; i++) {
        const int c = i * 64 + lane;
        const int row = c >> 5, col = wave * 128 + (c & 31) * 4;
        uint2 d;
        d.x = (vv[i].x & 0xFFFFu) | (vv[i].y << 16);
        d.y = (vv[i].z & 0xFFFFu) | (vv[i].w << 16);
        *(uint2*)&Hs[row][col] = d;
      }
    }
    __syncthreads();                                  // S2: Hs(t) complete
  }
}

// ---------------------------------------------------------------------------
// K3: logits = hs(bf16) @ Wv(bf16)^T + bias, MFMA 16x16x32.
// A is [t][b][h] (row = t*32+b); logical GEMM row m = b*128+t is remapped at
// the A-load only. A (4 MB) is L2/L3-hot from k_rec.
// ---------------------------------------------------------------------------
#define PM 128
#define PN 128
#define PK 32
#define PKP 40

__global__ __launch_bounds__(256) void k_proj_mfma(
    const __bf16* __restrict__ A,    // [4096][512], row = t*32+b
    const __bf16* __restrict__ Bw,   // [10000][512]
    const float* __restrict__ bias, float* __restrict__ C) {
  __shared__ __bf16 As[PM][PKP];
  __shared__ __bf16 Bs[PN][PKP];
  const int m0 = blockIdx.x * PM;
  const int n0 = blockIdx.y * PN;
  const int t = threadIdx.x;
  const int wave = t >> 6, lane = t & 63;
  const int wm = (wave & 1) * 64, wn = (wave >> 1) * 64;
  const int fm = lane & 15, fk = (lane >> 4) * 8;
  const int sr = t >> 2, sk = (t & 3) * 8;

  const int n1 = min(n0 + sr, Vx - 1);
  const int n2 = min(n0 + sr + 64, Vx - 1);
  const int g1 = m0 + sr, g2 = m0 + sr + 64;         // logical m = b*128+t
  const int r1 = ((g1 & 127) << 5) | (g1 >> 7);      // physical row t*32+b
  const int r2 = ((g2 & 127) << 5) | (g2 >> 7);

  f32x4 acc[4][4];
#pragma unroll
  for (int i = 0; i < 4; i++)
#pragma unroll
    for (int j = 0; j < 4; j++) acc[i][j] = (f32x4){0.f, 0.f, 0.f, 0.f};

  for (int k0 = 0; k0 < Hx; k0 += PK) {
    __syncthreads();
    *(bf16x8*)&As[sr][sk]      = *(const bf16x8*)&A[(size_t)r1 * Hx + k0 + sk];
    *(bf16x8*)&As[sr + 64][sk] = *(const bf16x8*)&A[(size_t)r2 * Hx + k0 + sk];
    *(bf16x8*)&Bs[sr][sk]      = *(const bf16x8*)&Bw[(size_t)n1 * Hx + k0 + sk];
    *(bf16x8*)&Bs[sr + 64][sk] = *(const bf16x8*)&Bw[(size_t)n2 * Hx + k0 + sk];
    __syncthreads();
    bf16x8 af[4], bfr[4];
#pragma unroll
    for (int i = 0; i < 4; i++) af[i]  = *(const bf16x8*)&As[wm + i * 16 + fm][fk];
#pragma unroll
    for (int j = 0; j < 4; j++) bfr[j] = *(const bf16x8*)&Bs[wn + j * 16 + fm][fk];
#pragma unroll
    for (int i = 0; i < 4; i++)
#pragma unroll
      for (int j = 0; j < 4; j++)
        acc[i][j] = MFMA16(af[i], bfr[j], acc[i][j], 0, 0, 0);
  }

  const int cr = (lane >> 4) * 4, cc = lane & 15;
#pragma unroll
  for (int i = 0; i < 4; i++) {
#pragma unroll
    for (int r = 0; r < 4; r++) {
      const int m = m0 + wm + i * 16 + cr + r;
      float* crow = C + (size_t)m * Vx;
#pragma unroll
      for (int j = 0; j < 4; j++) {
        const int n = n0 + wn + j * 16 + cc;
        if (n < Vx) crow[n] = acc[i][j][r] + bias[n];
      }
    }
  }
}

// ---------------------------------------------------------------------------
// Inputs (setup_inputs order):
//  0 text_vectors [32,512] f32   1 texts [32,128] i32   2 lengths (unused)
//  3 start_idx i32               4 emb_table [10000,256] f32
//  5 W_ih [2048,1280] 6 b_ih 7 W_hh [2048,512] 8 b_hh
//  9 Wo_w 10 Wo_b 11 Wh_w 12 Wh_b 13 Wc_w 14 Wc_b 15 Wv_w [10000,512] 16 Wv_b
// Output: logits [32,128,10000] f32. Workspace: ~23.4 MB.
// ---------------------------------------------------------------------------
extern "C" void kernel_launch(void* const* d_in, const int* in_sizes, int n_in,
                              void* d_out, int out_size, void* d_ws, size_t ws_size,
                              hipStream_t stream) {
  const float* tv     = (const float*)d_in[0];
  const int*   texts  = (const int*)d_in[1];
  const int*   sidx   = (const int*)d_in[3];
  const float* emb    = (const float*)d_in[4];
  const float* W_ih   = (const float*)d_in[5];
  const float* b_ih   = (const float*)d_in[6];
  const float* W_hh   = (const float*)d_in[7];
  const float* b_hh   = (const float*)d_in[8];
  const float* Wo_w   = (const float*)d_in[9];
  const float* Wo_b   = (const float*)d_in[10];
  const float* Wh_w   = (const float*)d_in[11];
  const float* Wh_b   = (const float*)d_in[12];
  const float* Wc_w   = (const float*)d_in[13];
  const float* Wc_b   = (const float*)d_in[14];
  const float* Wv_w   = (const float*)d_in[15];
  const float* Wv_b   = (const float*)d_in[16];
  float* out = (float*)d_out;

  float* ws     = (float*)d_ws;
  float* o      = ws;                 // 16384 f
  float* c0     = o + Bx * Hx;        // 16384 f
  float* constC = c0 + Hx * Bx;       // 65536 f
  uint32_t* tgd = (uint32_t*)(constC + (size_t)Bx * G4);  // 2*32*512 dwords
  __bf16* bfb   = (__bf16*)(ws + 98304 + 2 * Bx * Hx);    // 16B-aligned
  __bf16* hinit = bfb;                                // 32*512 initial h
  __bf16* hs2   = hinit + Bx * Hx;                    // 128*32*512, [t][b][h]
  __bf16* Wvb   = hs2 + (size_t)Bx * Tx * Hx;         // 10000*512
  __bf16* Whb   = Wvb + (size_t)Vx * Hx;              // 2048*512
  __bf16* embb  = Whb + (size_t)G4 * Hx;              // 10000*256
  __bf16* Wihb  = embb + (size_t)Vx * Ex;             // 2048*256

  hipLaunchKernelGGL(k_cvt, dim3((Vx * Hx / 4 + 255) / 256), dim3(256), 0, stream,
                     Wv_w, Wvb, Vx * Hx);
  hipLaunchKernelGGL(k_cvt, dim3((G4 * Hx / 4 + 255) / 256), dim3(256), 0, stream,
                     W_hh, Whb, G4 * Hx);
  hipLaunchKernelGGL(k_cvt, dim3((Vx * Ex / 4 + 255) / 256), dim3(256), 0, stream,
                     emb, embb, Vx * Ex);
  hipLaunchKernelGGL(k_cvt2d, dim3(G4 * Ex / 4 / 256), dim3(256), 0, stream,
                     W_ih, Wihb);
  hipLaunchKernelGGL(k_init, dim3(192), dim3(256), 0, stream,
                     tv, Wo_w, Wo_b, Wh_w, Wh_b, Wc_w, Wc_b, o, hinit, c0);
  hipLaunchKernelGGL(k_const, dim3(256), dim3(256), 0, stream,
                     tv, o, W_ih, b_ih, b_hh, constC, tgd);
  hipLaunchKernelGGL(k_rec, dim3(RBLK), dim3(256), 0, stream,
                     Whb, Wihb, embb, texts, sidx, constC, c0, hinit, hs2, tgd);
  hipLaunchKernelGGL(k_proj_mfma, dim3((Bx * Tx) / PM, (Vx + PN - 1) / PN), dim3(256), 0, stream,
                     hs2, Wvb, Wv_b, out);
}